// Round 9
// baseline (18260.544 us; speedup 1.0000x reference)
//
#include <hip/hip_runtime.h>
#include <math.h>

#define BB 64
#define TT 512
#define FF 32
#define HH 512
#define OO 680

#define H1SZ (HH*BB)   // 32768
#define H2SZ (OO*BB)   // 43520

// ws layout (floats): ping-pong state buffers, then barrier area.
// h1/c1/h2 are PAIR-INTERLEAVED: element (k,b) at [(k>>1)*128 + b*2 + (k&1)].
// c2 is plain [col][b] (only read by the output transpose).
#define H1_OFF 0
#define C1_OFF (H1_OFF + 2*H1SZ)
#define H2_OFF (C1_OFF + 2*H1SZ)
#define C2_OFF (H2_OFF + 2*H2SZ)
#define WS_FLOATS (C2_OFF + 2*H2SZ)   // 305152 floats
// barrier words: cnt[8] @ x*32, gcnt @ 256, flag replicas @ 320 + x*32
#define BAR_WORDS 640

#define NBLK 468
#define L1BLK 128      // blocks [0,128): L1, 4 cols each; [128,468): L2, 2 cols each

__device__ __forceinline__ float sigf(float x) { return 1.f / (1.f + expf(-x)); }

__device__ __forceinline__ float aload(const float* p) {
    return __hip_atomic_load(p, __ATOMIC_RELAXED, __HIP_MEMORY_SCOPE_AGENT);
}
__device__ __forceinline__ void astore(float* p, float v) {
    __hip_atomic_store(p, v, __ATOMIC_RELAXED, __HIP_MEMORY_SCOPE_AGENT);
}
// 8-byte coherence-point load: (k, k+1) pair in one instruction.
__device__ __forceinline__ float2 aload2(const float* p) {
    unsigned long long v = __hip_atomic_load((const unsigned long long*)p,
                                             __ATOMIC_RELAXED, __HIP_MEMORY_SCOPE_AGENT);
    float2 r;
    r.x = __uint_as_float((unsigned)v);
    r.y = __uint_as_float((unsigned)(v >> 32));
    return r;
}

// Grid barrier, generation = s+1. No threadfences (cross-block data moves via
// coherence-point accesses). s_waitcnt(0) orders act stores before arrival.
__device__ __forceinline__ void gridbar(unsigned* bar, int blk, int s) {
    __syncthreads();
    if (threadIdx.x == 0) {
        __builtin_amdgcn_s_waitcnt(0);   // all prior stores acked at LLC
        const int x = blk & 7;
        const unsigned gsz = (x < 4) ? 59u : 58u;   // 468 = 4*59 + 4*58
        unsigned* cnt  = bar + x * 32;
        unsigned* gcnt = bar + 256;
        unsigned* flag = bar + 320 + x * 32;
        const unsigned a = __hip_atomic_fetch_add(cnt, 1u, __ATOMIC_RELAXED, __HIP_MEMORY_SCOPE_AGENT);
        if (a == gsz - 1u) {
            __hip_atomic_store(cnt, 0u, __ATOMIC_RELAXED, __HIP_MEMORY_SCOPE_AGENT);
            const unsigned ga = __hip_atomic_fetch_add(gcnt, 1u, __ATOMIC_RELAXED, __HIP_MEMORY_SCOPE_AGENT);
            if (ga == 7u) {
                __hip_atomic_store(gcnt, 0u, __ATOMIC_RELAXED, __HIP_MEMORY_SCOPE_AGENT);
                #pragma unroll
                for (int r = 0; r < 8; ++r)
                    __hip_atomic_store(bar + 320 + r * 32, (unsigned)(s + 1), __ATOMIC_RELAXED, __HIP_MEMORY_SCOPE_AGENT);
            }
        }
        while (__hip_atomic_load(flag, __ATOMIC_RELAXED, __HIP_MEMORY_SCOPE_AGENT) < (unsigned)(s + 1))
            __builtin_amdgcn_s_sleep(2);
    }
    __syncthreads();
}

// acc[0..NR) += W[r][k] * act[k][lane]; act pair-interleaved, read as float2
// at the coherence point. (k - kofs) is even at all call boundaries.
template<int NR, int WL, int U>
__device__ __forceinline__ void accum_seg(const float* __restrict__ act, int kA, int kB,
                                          const float* wl, int kofs, int lane, float* acc)
{
    #pragma unroll U
    for (int k = kA; k < kB; k += 4) {
        const float* ap = act + (size_t)((k - kofs) >> 1) * 128 + lane * 2;
        const float2 a01 = aload2(ap);
        const float2 a23 = aload2(ap + 128);
        #pragma unroll
        for (int r = 0; r < NR; ++r) {
            const float4 w = *(const float4*)(wl + r * WL + k);
            acc[r] = fmaf(a23.y, w.w, fmaf(a23.x, w.z, fmaf(a01.y, w.y, fmaf(a01.x, w.x, acc[r]))));
        }
    }
}

// Persistent kernel, all 512 steps, software-skewed:
//   iter s: L1 blocks compute step s; L2 blocks compute step s-1;
//   L1 blocks also transpose c2(s-2) -> out (full-line coalesced writes).
__global__ __launch_bounds__(256, 2)
void rnn_persistent(const float* __restrict__ data,
    const float* __restrict__ Wih1, const float* __restrict__ Whh1,
    const float* __restrict__ bih1, const float* __restrict__ bhh1,
    const float* __restrict__ Wih2, const float* __restrict__ Whh2,
    const float* __restrict__ bih2, const float* __restrict__ bhh2,
    float* __restrict__ ws, float* __restrict__ out)
{
    __shared__ float wlds[9536];          // L1: 16*544=8704; L2: 8*1192=9536 floats
    __shared__ float part[4][16][BB];     // 16 KB (L2 uses [4][8][64])

    const int tid = threadIdx.x, wv = tid >> 6, lane = tid & 63;
    const int blk = blockIdx.x;
    const bool isL1 = blk < L1BLK;

    float* h1b = ws + H1_OFF;
    float* c1b = ws + C1_OFF;
    float* h2b = ws + H2_OFF;
    float* c2b = ws + C2_OFF;
    unsigned* bar = (unsigned*)(ws + WS_FLOATS);

    // ---- one-time weight preload (plain loads; L2 stays clean & hot) ----
    if (isL1) {
        const int c0 = 4 * blk;
        for (int idx = tid; idx < 16 * 544; idx += 256) {
            const int r = idx / 544, k = idx - r * 544;
            const int row = (r & 3) * HH + c0 + (r >> 2);
            wlds[idx] = (k < FF) ? Wih1[(size_t)row * FF + k]
                                 : Whh1[(size_t)row * HH + (k - FF)];
        }
    } else {
        const int c0 = 2 * (blk - L1BLK);
        for (int idx = tid; idx < 8 * 1192; idx += 256) {
            const int r = idx / 1192, k = idx - r * 1192;
            const int row = (r & 3) * OO + c0 + (r >> 2);
            wlds[idx] = (k < HH) ? Wih2[(size_t)row * HH + k]
                                 : Whh2[(size_t)row * OO + (k - HH)];
        }
    }
    __syncthreads();

    // ---- hoist per-column epilogue constants; cell state lives in registers ----
    const int c_ = tid >> 6, b_ = tid & 63;
    const int ncols = isL1 ? 4 : 2;
    int mycol = 0;
    float bsum[4] = {0.f, 0.f, 0.f, 0.f};
    float creg = 0.f;                     // c1[mycol][b_] or c2[mycol][b_]
    if (c_ < ncols) {
        if (isL1) {
            mycol = 4 * blk + c_;
            #pragma unroll
            for (int g = 0; g < 4; ++g) bsum[g] = bih1[g * HH + mycol] + bhh1[g * HH + mycol];
        } else {
            mycol = 2 * (blk - L1BLK) + c_;
            #pragma unroll
            for (int g = 0; g < 4; ++g) bsum[g] = bih2[g * OO + mycol] + bhh2[g * OO + mycol];
        }
    }
    // pair-layout write offset for this thread's (mycol, b_)
    const size_t pairoff = (size_t)(mycol >> 1) * 128 + b_ * 2 + (mycol & 1);

    // transpose-phase constants (L1 blocks): 512 waves = 64 batches x 8 col-segments
    const int wgid = blk * 4 + wv;            // 0..511 (L1 only)
    const int tb   = wgid >> 3;               // batch 0..63
    const int tc0  = (wgid & 7) * 85;         // col segment start (680 = 8*85)

    for (int s = 0; s <= TT + 1; ++s) {
        const int A = s & 1, Bx = A ^ 1;
        if (isL1) {
            // ---- output transpose: c2(step s-2) -> out, full-line NT writes ----
            if (s >= 2) {
                const int u2 = s - 2;
                const float* src = c2b + (size_t)Bx * H2SZ;   // c2(u2) in buffer (s-1)&1
                float* dst = out + (size_t)tb * (TT * OO) + (size_t)u2 * OO;
                const int ca  = tc0 + lane;
                const int cb2 = tc0 + 64 + lane;
                const float v0 = aload(src + (size_t)ca * BB + tb);
                const float v1 = (lane < 21) ? aload(src + (size_t)cb2 * BB + tb) : 0.f;
                __builtin_nontemporal_store(v0, dst + ca);
                if (lane < 21) __builtin_nontemporal_store(v1, dst + cb2);
            }
            // ---- layer-1 compute, step s ----
            if (s < TT) {
                float acc[16];
                #pragma unroll
                for (int r = 0; r < 16; ++r) acc[r] = 0.f;
                const int k0 = wv * 136, k1 = k0 + 136;   // K=544 = [x:32 | h1:512]
                if (wv == 0) {  // x segment (read-only input, plain loads)
                    const float* xp = data + (size_t)lane * (TT * FF) + (size_t)s * FF;
                    #pragma unroll
                    for (int k = 0; k < FF; k += 4) {
                        const float a0 = xp[k], a1 = xp[k+1], a2 = xp[k+2], a3 = xp[k+3];
                        #pragma unroll
                        for (int r = 0; r < 16; ++r) {
                            const float4 w = *(const float4*)(wlds + r * 544 + k);
                            acc[r] = fmaf(a3, w.w, fmaf(a2, w.z, fmaf(a1, w.y, fmaf(a0, w.x, acc[r]))));
                        }
                    }
                }
                const int ha = (wv == 0) ? FF : k0;
                accum_seg<16, 544, 4>(h1b + (size_t)A * H1SZ, ha, k1, wlds, FF, lane, acc);
                #pragma unroll
                for (int r = 0; r < 16; ++r) part[wv][r][lane] = acc[r];
            }
            __syncthreads();
            if (s < TT) {   // all 256 threads: 4 cols x 64 batch
                float gt[4];
                #pragma unroll
                for (int g = 0; g < 4; ++g) {
                    const int r = c_ * 4 + g;
                    gt[g] = part[0][r][b_] + part[1][r][b_] + part[2][r][b_] + part[3][r][b_] + bsum[g];
                }
                const float ig = sigf(gt[0]), fg = sigf(gt[1]);
                const float gg = tanhf(gt[2]), og = sigf(gt[3]);
                const float cn = fg * creg + ig * gg;
                const float hn = og * tanhf(cn);
                creg = cn;
                astore(c1b + (size_t)Bx * H1SZ + pairoff, cn);
                astore(h1b + (size_t)Bx * H1SZ + pairoff, hn);
            }
        } else {
            // ---- layer-2 compute, step s-1 ----
            if (s >= 1 && s <= TT) {
                float acc[8];
                #pragma unroll
                for (int r = 0; r < 8; ++r) acc[r] = 0.f;
                // K=1192 = [c1:512 | h2:680]; wave ranges {0,300,600,896,1192}
                const int k0 = (wv < 2) ? wv * 300 : 600 + (wv - 2) * 296;
                const int k1 = (wv == 0) ? 300 : (wv == 1) ? 600 : (wv == 2) ? 896 : 1192;
                if (k0 < HH) {
                    const int cb = (k1 < HH) ? k1 : HH;
                    accum_seg<8, 1192, 8>(c1b + (size_t)A * H1SZ, k0, cb, wlds, 0, lane, acc);
                }
                if (k1 > HH) {
                    const int ha = (k0 > HH) ? k0 : HH;
                    accum_seg<8, 1192, 8>(h2b + (size_t)Bx * H2SZ, ha, k1, wlds, HH, lane, acc);
                }
                #pragma unroll
                for (int r = 0; r < 8; ++r) part[wv][r][lane] = acc[r];
            }
            __syncthreads();
            if (s >= 1 && s <= TT && tid < 128) {   // 2 cols x 64 batch
                float gt[4];
                #pragma unroll
                for (int g = 0; g < 4; ++g) {
                    const int r = c_ * 4 + g;
                    gt[g] = part[0][r][b_] + part[1][r][b_] + part[2][r][b_] + part[3][r][b_] + bsum[g];
                }
                const float ig = sigf(gt[0]), fg = sigf(gt[1]);
                const float gg = tanhf(gt[2]), og = sigf(gt[3]);
                const float cn = fg * creg + ig * gg;
                const float hn = og * tanhf(cn);
                creg = cn;
                astore(c2b + (size_t)A * H2SZ + (size_t)mycol * BB + b_, cn);  // plain layout (transpose reads it)
                astore(h2b + (size_t)A * H2SZ + pairoff, hn);                  // pair layout (L2 accum reads it)
            }
        }
        if (s <= TT) gridbar(bar, blk, s);
    }
}

extern "C" void kernel_launch(void* const* d_in, const int* in_sizes, int n_in,
                              void* d_out, int out_size, void* d_ws, size_t ws_size,
                              hipStream_t stream)
{
    const float* data = (const float*)d_in[0];
    const float* Wih1 = (const float*)d_in[1];
    const float* Whh1 = (const float*)d_in[2];
    const float* bih1 = (const float*)d_in[3];
    const float* bhh1 = (const float*)d_in[4];
    const float* Wih2 = (const float*)d_in[5];
    const float* Whh2 = (const float*)d_in[6];
    const float* bih2 = (const float*)d_in[7];
    const float* bhh2 = (const float*)d_in[8];
    float* out = (float*)d_out;
    float* ws  = (float*)d_ws;

    // zero LSTM state + barrier words (graph-capture-legal, replay-safe)
    hipMemsetAsync(ws, 0, (size_t)WS_FLOATS * sizeof(float) + (size_t)BAR_WORDS * sizeof(unsigned), stream);
    rnn_persistent<<<NBLK, 256, 0, stream>>>(data,
                                             Wih1, Whh1, bih1, bhh1,
                                             Wih2, Whh2, bih2, bhh2,
                                             ws, out);
}

// Round 10
// 14817.804 us; speedup vs baseline: 1.2323x; 1.2323x over previous
//
#include <hip/hip_runtime.h>
#include <math.h>

#define BB 64
#define TT 512
#define FF 32
#define HH 512
#define OO 680

typedef _Float16 half8 __attribute__((ext_vector_type(8)));
typedef float f32x4 __attribute__((ext_vector_type(4)));

// ---- ws byte layout ----
// fp16 act slabs (ping-pong), then barrier words, then fp16 weight copies.
#define H1BUF   65536u                 // [64][512] fp16
#define C1BUF   65536u                 // [64][512] fp16
#define H2BUF   90112u                 // [64][704] fp16 (680 cols + zero pad)
#define H1S_OFF 0u
#define C1S_OFF 131072u
#define H2S_OFF 262144u
#define BAR_OFF 442368u                // 2560 B of barrier words
#define WF1_OFF 444928u                // [2048][544] fp16  (row = g*512 + col)
#define WF2_OFF 2673152u               // [4][688][1216] fp16 (col/k zero-padded)
#define MEMSET_BYTES WF1_OFF

#define L1B  16                        // blocks 0..15: layer-1, 32 cols each
#define NBLK 59                        // + 43 layer-2 blocks, 16 cols each

__device__ __forceinline__ float sigf(float x) { return 1.f / (1.f + expf(-x)); }

// coherence-point (LLC) primitives — no cache maintenance needed (R8 lesson)
__device__ __forceinline__ unsigned long long aload8(const void* p) {
    return __hip_atomic_load((const unsigned long long*)p, __ATOMIC_RELAXED, __HIP_MEMORY_SCOPE_AGENT);
}
__device__ __forceinline__ void astore8(void* p, unsigned long long v) {
    __hip_atomic_store((unsigned long long*)p, v, __ATOMIC_RELAXED, __HIP_MEMORY_SCOPE_AGENT);
}
__device__ __forceinline__ half8 ld_act(const char* p) {   // 16B act fragment as 2x8B LLC loads
    union { unsigned long long u[2]; half8 h; } t;
    t.u[0] = aload8(p); t.u[1] = aload8(p + 8);
    return t.h;
}
__device__ __forceinline__ void cvt_store2(char* dst, float v0, float v1) {
    union { _Float16 h[2]; unsigned u; } t;
    t.h[0] = (_Float16)v0; t.h[1] = (_Float16)v1;
    __hip_atomic_store((unsigned*)dst, t.u, __ATOMIC_RELAXED, __HIP_MEMORY_SCOPE_AGENT);
}
__device__ __forceinline__ unsigned long long pack4h(float a, float b, float c, float d) {
    union { _Float16 h[4]; unsigned long long u; } t;
    t.h[0] = (_Float16)a; t.h[1] = (_Float16)b; t.h[2] = (_Float16)c; t.h[3] = (_Float16)d;
    return t.u;
}

// Grid barrier (R8-proven): relaxed RMW arrival on 8 split counters, relaxed
// LOAD polling on 8 replicated flags, no fences in the loop.
__device__ __forceinline__ void gridbar(unsigned* bar, int blk, unsigned gen) {
    __syncthreads();
    if (threadIdx.x == 0) {
        __builtin_amdgcn_s_waitcnt(0);
        const int x = blk & 7;
        const unsigned gsz = (x < 3) ? 8u : 7u;   // 59 = 3*8 + 5*7
        unsigned* cnt  = bar + x * 32;
        unsigned* gcnt = bar + 256;
        unsigned* flag = bar + 320 + x * 32;
        const unsigned a = __hip_atomic_fetch_add(cnt, 1u, __ATOMIC_RELAXED, __HIP_MEMORY_SCOPE_AGENT);
        if (a == gsz - 1u) {
            __hip_atomic_store(cnt, 0u, __ATOMIC_RELAXED, __HIP_MEMORY_SCOPE_AGENT);
            const unsigned ga = __hip_atomic_fetch_add(gcnt, 1u, __ATOMIC_RELAXED, __HIP_MEMORY_SCOPE_AGENT);
            if (ga == 7u) {
                __hip_atomic_store(gcnt, 0u, __ATOMIC_RELAXED, __HIP_MEMORY_SCOPE_AGENT);
                #pragma unroll
                for (int r = 0; r < 8; ++r)
                    __hip_atomic_store(bar + 320 + r * 32, gen, __ATOMIC_RELAXED, __HIP_MEMORY_SCOPE_AGENT);
            }
        }
        while (__hip_atomic_load(flag, __ATOMIC_RELAXED, __HIP_MEMORY_SCOPE_AGENT) < gen)
            __builtin_amdgcn_s_sleep(2);
    }
    __syncthreads();
}

#define MFMA4(B) \
    acc0 = __builtin_amdgcn_mfma_f32_16x16x32_f16(*(const half8*)(wa0 + koff), (B), acc0, 0, 0, 0); \
    acc1 = __builtin_amdgcn_mfma_f32_16x16x32_f16(*(const half8*)(wa1 + koff), (B), acc1, 0, 0, 0); \
    acc2 = __builtin_amdgcn_mfma_f32_16x16x32_f16(*(const half8*)(wa2 + koff), (B), acc2, 0, 0, 0); \
    acc3 = __builtin_amdgcn_mfma_f32_16x16x32_f16(*(const half8*)(wa3 + koff), (B), acc3, 0, 0, 0);

// Persistent MFMA kernel. 59 blocks x 512 threads.
//  blocks [0,16):  L1, 32 cols; 8 waves = 4 batch-frags x 2 gate-pairs (full K)
//  blocks [16,59): L2, 16 cols; 8 waves = 4 batch-frags x 2 K-halves
// Skew: iter s runs L1 step s (s<TT) and L2 step s-1 (s>=1); L2 writes `out`
// directly (full-line float4 per block).
__global__ __launch_bounds__(512, 1)
void rnn_mfma(const float* __restrict__ data,
    const float* __restrict__ Wih1, const float* __restrict__ Whh1,
    const float* __restrict__ bih1, const float* __restrict__ bhh1,
    const float* __restrict__ Wih2, const float* __restrict__ Whh2,
    const float* __restrict__ bih2, const float* __restrict__ bhh2,
    char* __restrict__ wsb, float* __restrict__ out)
{
    __shared__ f32x4 part[4][4][64];   // 16 KB: [wavepair][frag][lane]

    const int tid = threadIdx.x, wv = tid >> 6, l = tid & 63;
    const int hi = l >> 4, lo = l & 15;
    const int blk = blockIdx.x;
    const bool isL1 = blk < L1B;
    unsigned* bar = (unsigned*)(wsb + BAR_OFF);

    const int bfrag = wv & 3;
    const int b  = bfrag * 16 + lo;    // batch index this lane carries
    const int kg = hi * 8;             // k-offset within a 32-wide k-step

    // ---------------- bias hoist (epilogue waves only) ----------------
    const int c0 = isL1 ? blk * 32 : (blk - L1B) * 16;
    float bs[2][4][4];                 // L1: [chi][r][g]; L2 uses [0][r][g]
    if (wv < 4) {
        if (isL1) {
            #pragma unroll
            for (int chi = 0; chi < 2; ++chi)
                #pragma unroll
                for (int r = 0; r < 4; ++r) {
                    const int col = c0 + chi * 16 + hi * 4 + r;
                    #pragma unroll
                    for (int g = 0; g < 4; ++g)
                        bs[chi][r][g] = bih1[g * HH + col] + bhh1[g * HH + col];
                }
        } else {
            #pragma unroll
            for (int r = 0; r < 4; ++r) {
                const int col = c0 + hi * 4 + r;
                const bool ok = col < OO;
                #pragma unroll
                for (int g = 0; g < 4; ++g)
                    bs[0][r][g] = ok ? (bih2[g * OO + col] + bhh2[g * OO + col]) : 0.f;
            }
        }
    }

    // ---------------- one-time weight conversion fp32 -> fp16 ----------------
    {
        const int G = NBLK * 512;
        const int t0 = blk * 512 + tid;
        for (int i = t0; i < (2048 * 544) / 2; i += G) {
            const int flat = 2 * i, row = flat / 544, k = flat - row * 544;
            const float v0 = (k < FF)     ? Wih1[(size_t)row * FF + k]     : Whh1[(size_t)row * HH + (k - FF)];
            const float v1 = (k + 1 < FF) ? Wih1[(size_t)row * FF + k + 1] : Whh1[(size_t)row * HH + (k + 1 - FF)];
            cvt_store2(wsb + WF1_OFF + (size_t)flat * 2, v0, v1);
        }
        for (int i = t0; i < (4 * 688 * 1216) / 2; i += G) {
            const int flat = 2 * i;
            const int g = flat / (688 * 1216), rem = flat - g * (688 * 1216);
            const int c = rem / 1216, k = rem - c * 1216;
            float v0 = 0.f, v1 = 0.f;
            if (c < OO) {
                if (k < HH) v0 = Wih2[((size_t)g * OO + c) * HH + k];
                else if (k < 1192) v0 = Whh2[((size_t)g * OO + c) * OO + (k - HH)];
                if (k + 1 < HH) v1 = Wih2[((size_t)g * OO + c) * HH + k + 1];
                else if (k + 1 < 1192) v1 = Whh2[((size_t)g * OO + c) * OO + (k + 1 - HH)];
            }
            cvt_store2(wsb + WF2_OFF + (size_t)flat * 2, v0, v1);
        }
        gridbar(bar, blk, 1u);
        __threadfence();   // ONE-TIME acquire: drop stale/poisoned L2 lines so
                           // plain fp16-weight loads below read the converted data.
    }

    // ---------------- A-operand (weight) base pointers ----------------
    const char *wa0, *wa1, *wa2, *wa3;
    if (isL1) {
        const int gh = wv >> 2;        // gate-pair: 0 -> gates {0,1}, 1 -> {2,3}
        #define WA1(f) (wsb + WF1_OFF + ((size_t)((((gh*4+(f))>>1)*HH + c0 + ((gh*4+(f))&1)*16 + lo) * 544 + kg) * 2))
        wa0 = WA1(0); wa1 = WA1(1); wa2 = WA1(2); wa3 = WA1(3);
    } else {
        #define WA2(f) (wsb + WF2_OFF + ((size_t)(((f)*688 + c0 + lo) * 1216 + kg) * 2))
        wa0 = WA2(0); wa1 = WA2(1); wa2 = WA2(2); wa3 = WA2(3);
    }
    const int kh = wv >> 2;            // L2: K-half

    float cr[8] = {0.f,0.f,0.f,0.f,0.f,0.f,0.f,0.f};   // register cell state

    for (int s = 0; s <= TT; ++s) {
        const int A = s & 1, Bx = A ^ 1;
        const bool active = isL1 ? (s < TT) : (s >= 1);
        f32x4 acc0 = {0,0,0,0}, acc1 = {0,0,0,0}, acc2 = {0,0,0,0}, acc3 = {0,0,0,0};

        if (active) {
            if (isL1) {
                // k-step 0: x from `data` (fp32, read-only, plain loads)
                {
                    const float* xp = data + (size_t)b * (TT * FF) + (size_t)s * FF + kg;
                    const float4 xa = *(const float4*)xp;
                    const float4 xb = *(const float4*)(xp + 4);
                    half8 bxf;
                    bxf[0] = (_Float16)xa.x; bxf[1] = (_Float16)xa.y;
                    bxf[2] = (_Float16)xa.z; bxf[3] = (_Float16)xa.w;
                    bxf[4] = (_Float16)xb.x; bxf[5] = (_Float16)xb.y;
                    bxf[6] = (_Float16)xb.z; bxf[7] = (_Float16)xb.w;
                    const size_t koff = 0;
                    MFMA4(bxf);
                }
                // k-steps 1..16: h1 slab
                const char* bp = wsb + H1S_OFF + (size_t)A * H1BUF + ((size_t)b * 512 + kg) * 2;
                #pragma unroll 4
                for (int ks = 1; ks <= 16; ++ks) {
                    const half8 bf = ld_act(bp + (size_t)(ks - 1) * 64);
                    const size_t koff = (size_t)ks * 64;
                    MFMA4(bf);
                }
            } else {
                if (kh == 0) {
                    const char* bp = wsb + C1S_OFF + (size_t)A * C1BUF + ((size_t)b * 512 + kg) * 2;
                    #pragma unroll 4
                    for (int ks = 0; ks < 16; ++ks) {
                        const half8 bf = ld_act(bp + (size_t)ks * 64);
                        const size_t koff = (size_t)ks * 64;
                        MFMA4(bf);
                    }
                    const char* bp2 = wsb + H2S_OFF + (size_t)Bx * H2BUF + ((size_t)b * 704 + kg) * 2;
                    #pragma unroll
                    for (int ks = 16; ks < 19; ++ks) {
                        const half8 bf = ld_act(bp2 + (size_t)(ks - 16) * 64);
                        const size_t koff = (size_t)ks * 64;
                        MFMA4(bf);
                    }
                } else {
                    const char* bp2 = wsb + H2S_OFF + (size_t)Bx * H2BUF + ((size_t)b * 704 + kg) * 2;
                    #pragma unroll 4
                    for (int ks = 19; ks < 38; ++ks) {
                        const half8 bf = ld_act(bp2 + (size_t)(ks - 16) * 64);
                        const size_t koff = (size_t)ks * 64;
                        MFMA4(bf);
                    }
                }
            }
        }

        // ---- partial exchange: upper waves publish their C fragments ----
        if (wv >= 4 && active) {
            part[wv - 4][0][l] = acc0;
            part[wv - 4][1][l] = acc1;
            part[wv - 4][2][l] = acc2;
            part[wv - 4][3][l] = acc3;
        }
        __syncthreads();

        // ---- epilogue (lower waves): gates are lane-local ----
        if (wv < 4 && active) {
            if (isL1) {
                #pragma unroll
                for (int chi = 0; chi < 2; ++chi) {
                    const f32x4 o0 = (chi == 0) ? acc0 : acc1;   // gate 0
                    const f32x4 o1 = (chi == 0) ? acc2 : acc3;   // gate 1
                    const f32x4 p0 = part[wv][chi][l];           // gate 2
                    const f32x4 p1 = part[wv][2 + chi][l];       // gate 3
                    float cn[4], hn[4];
                    #pragma unroll
                    for (int r = 0; r < 4; ++r) {
                        const float ig = sigf(o0[r] + bs[chi][r][0]);
                        const float fg = sigf(o1[r] + bs[chi][r][1]);
                        const float gg = tanhf(p0[r] + bs[chi][r][2]);
                        const float og = sigf(p1[r] + bs[chi][r][3]);
                        const float c = fg * cr[chi * 4 + r] + ig * gg;
                        cr[chi * 4 + r] = c;
                        cn[r] = c; hn[r] = og * tanhf(c);
                    }
                    const size_t off = ((size_t)b * 512 + c0 + chi * 16 + hi * 4) * 2;
                    astore8(wsb + H1S_OFF + (size_t)Bx * H1BUF + off, pack4h(hn[0], hn[1], hn[2], hn[3]));
                    astore8(wsb + C1S_OFF + (size_t)Bx * C1BUF + off, pack4h(cn[0], cn[1], cn[2], cn[3]));
                }
            } else {
                const int u = s - 1;
                const f32x4 p0 = part[wv][0][l], p1 = part[wv][1][l];
                const f32x4 p2 = part[wv][2][l], p3 = part[wv][3][l];
                float cn[4], hn[4];
                #pragma unroll
                for (int r = 0; r < 4; ++r) {
                    const float ig = sigf(acc0[r] + p0[r] + bs[0][r][0]);
                    const float fg = sigf(acc1[r] + p1[r] + bs[0][r][1]);
                    const float gg = tanhf(acc2[r] + p2[r] + bs[0][r][2]);
                    const float og = sigf(acc3[r] + p3[r] + bs[0][r][3]);
                    const float c = fg * cr[r] + ig * gg;
                    cr[r] = c;
                    cn[r] = c; hn[r] = og * tanhf(c);
                }
                const int cc = c0 + hi * 4;
                if (cc < OO) {
                    const f32x4 q = {cn[0], cn[1], cn[2], cn[3]};
                    __builtin_nontemporal_store(q, (f32x4*)(out + (size_t)b * (TT * OO) + (size_t)u * OO + cc));
                    astore8(wsb + H2S_OFF + (size_t)A * H2BUF + ((size_t)b * 704 + cc) * 2,
                            pack4h(hn[0], hn[1], hn[2], hn[3]));
                }
            }
        }
        gridbar(bar, blk, (unsigned)(s + 2));
    }
}

extern "C" void kernel_launch(void* const* d_in, const int* in_sizes, int n_in,
                              void* d_out, int out_size, void* d_ws, size_t ws_size,
                              hipStream_t stream)
{
    const float* data = (const float*)d_in[0];
    const float* Wih1 = (const float*)d_in[1];
    const float* Whh1 = (const float*)d_in[2];
    const float* bih1 = (const float*)d_in[3];
    const float* bhh1 = (const float*)d_in[4];
    const float* Wih2 = (const float*)d_in[5];
    const float* Whh2 = (const float*)d_in[6];
    const float* bih2 = (const float*)d_in[7];
    const float* bhh2 = (const float*)d_in[8];
    float* out = (float*)d_out;
    char* wsb  = (char*)d_ws;

    // zero act slabs + barrier words only (weights are re-converted each call)
    hipMemsetAsync(wsb, 0, MEMSET_BYTES, stream);
    rnn_mfma<<<NBLK, 512, 0, stream>>>(data,
                                       Wih1, Whh1, bih1, bhh1,
                                       Wih2, Whh2, bih2, bhh2,
                                       wsb, out);
}

// Round 11
// 4660.994 us; speedup vs baseline: 3.9177x; 3.1791x over previous
//
#include <hip/hip_runtime.h>
#include <math.h>

#define BB 64
#define TT 512
#define FF 32
#define HH 512
#define OO 680

typedef _Float16 half8 __attribute__((ext_vector_type(8)));
typedef float f32x4 __attribute__((ext_vector_type(4)));

// ---- ws layout: act slabs in MFMA-B-fragment tile order, ping-pong ----
// tile(ks,bfrag) = 1KB; lane l owns 16B at l*16 holding elements
// (k = ks*32 + (l>>4)*8 + j, batch = bfrag*16 + (l&15)), j=0..7.
#define H1SLAB 65536u                  // 16 k-tiles x 4 bfrag
#define C1SLAB 65536u
#define H2SLAB 90112u                  // 22 k-tiles (680 cols zero-padded to 704)
#define H1S_OFF 0u
#define C1S_OFF 131072u
#define H2S_OFF 262144u
#define BAR_OFF 442368u
#define MEMSET_BYTES 444928u

#define L1B  16                        // blocks [0,16): L1, 32 cols each
#define NBLK 59                        // blocks [16,59): L2, 16 cols each
#define LDS_BYTES 159744u              // L2: 152KB weight slab + 4KB exchange

__device__ __forceinline__ float sigf(float x) { return 1.f / (1.f + expf(-x)); }

__device__ __forceinline__ unsigned long long aload8(const void* p) {
    return __hip_atomic_load((const unsigned long long*)p, __ATOMIC_RELAXED, __HIP_MEMORY_SCOPE_AGENT);
}
__device__ __forceinline__ void astore8(void* p, unsigned long long v) {
    __hip_atomic_store((unsigned long long*)p, v, __ATOMIC_RELAXED, __HIP_MEMORY_SCOPE_AGENT);
}
__device__ __forceinline__ half8 ld_act(const char* p) {
    union { unsigned long long u[2]; half8 h; } t;
    t.u[0] = aload8(p); t.u[1] = aload8(p + 8);
    return t.h;
}
__device__ __forceinline__ unsigned pack2h(float a, float b) {
    union { _Float16 h[2]; unsigned u; } t;
    t.h[0] = (_Float16)a; t.h[1] = (_Float16)b; return t.u;
}
__device__ __forceinline__ unsigned long long pack4h(float a, float b, float c, float d) {
    union { _Float16 h[4]; unsigned long long u; } t;
    t.h[0] = (_Float16)a; t.h[1] = (_Float16)b; t.h[2] = (_Float16)c; t.h[3] = (_Float16)d;
    return t.u;
}

// Grid barrier (R8-proven): relaxed RMW arrival, relaxed LOAD polling, no fences.
__device__ __forceinline__ void gridbar(unsigned* bar, int blk, unsigned gen) {
    __syncthreads();
    if (threadIdx.x == 0) {
        __builtin_amdgcn_s_waitcnt(0);
        const int x = blk & 7;
        const unsigned gsz = (x < 3) ? 8u : 7u;   // 59 = 3*8 + 5*7
        unsigned* cnt  = bar + x * 32;
        unsigned* gcnt = bar + 256;
        unsigned* flag = bar + 320 + x * 32;
        const unsigned a = __hip_atomic_fetch_add(cnt, 1u, __ATOMIC_RELAXED, __HIP_MEMORY_SCOPE_AGENT);
        if (a == gsz - 1u) {
            __hip_atomic_store(cnt, 0u, __ATOMIC_RELAXED, __HIP_MEMORY_SCOPE_AGENT);
            const unsigned ga = __hip_atomic_fetch_add(gcnt, 1u, __ATOMIC_RELAXED, __HIP_MEMORY_SCOPE_AGENT);
            if (ga == 7u) {
                __hip_atomic_store(gcnt, 0u, __ATOMIC_RELAXED, __HIP_MEMORY_SCOPE_AGENT);
                #pragma unroll
                for (int r = 0; r < 8; ++r)
                    __hip_atomic_store(bar + 320 + r * 32, gen, __ATOMIC_RELAXED, __HIP_MEMORY_SCOPE_AGENT);
            }
        }
        while (__hip_atomic_load(flag, __ATOMIC_RELAXED, __HIP_MEMORY_SCOPE_AGENT) < gen)
            __builtin_amdgcn_s_sleep(2);
    }
    __syncthreads();
}

#define MFMA4(B, AT) \
    acc0 = __builtin_amdgcn_mfma_f32_16x16x32_f16(*(const half8*)((AT)       ), (B), acc0, 0, 0, 0); \
    acc1 = __builtin_amdgcn_mfma_f32_16x16x32_f16(*(const half8*)((AT) + 1024), (B), acc1, 0, 0, 0); \
    acc2 = __builtin_amdgcn_mfma_f32_16x16x32_f16(*(const half8*)((AT) + 2048), (B), acc2, 0, 0, 0); \
    acc3 = __builtin_amdgcn_mfma_f32_16x16x32_f16(*(const half8*)((AT) + 3072), (B), acc3, 0, 0, 0);

// Persistent MFMA kernel, 59 blocks x 512 threads, weights LDS-resident.
//  L1 blocks: 32 cols; waves = 4 bfrag x 2 gate-pairs; LDS tiles ks*8 + gh*4 + f.
//  L2 blocks: 16 cols; waves = 4 bfrag x 2 K-halves;   LDS tiles ks*4 + gate.
__global__ __launch_bounds__(512, 1)
void rnn_mfma(const float* __restrict__ data,
    const float* __restrict__ Wih1, const float* __restrict__ Whh1,
    const float* __restrict__ bih1, const float* __restrict__ bhh1,
    const float* __restrict__ Wih2, const float* __restrict__ Whh2,
    const float* __restrict__ bih2, const float* __restrict__ bhh2,
    char* __restrict__ wsb, float* __restrict__ out)
{
    extern __shared__ char lds[];
    const int tid = threadIdx.x, wv = tid >> 6, l = tid & 63;
    const int hi = l >> 4, lo = l & 15;
    const int blk = blockIdx.x;
    const bool isL1 = blk < L1B;
    unsigned* bar = (unsigned*)(wsb + BAR_OFF);
    const int bfrag = wv & 3;
    const int b = bfrag * 16 + lo;
    const int c0 = isL1 ? blk * 32 : (blk - L1B) * 16;

    // ---- one-time: convert this block's weight slab fp32->fp16 into LDS ----
    if (isL1) {
        for (int u = tid; u < 136 * 256; u += 512) {
            const int tile = u >> 8, w = u & 255;
            const int ll = w >> 2, jj = w & 3;
            const int ks = tile >> 3, rest = tile & 7;
            const int gate = rest >> 1, chi = rest & 1;
            const int col = c0 + chi * 16 + (ll & 15);
            const int row = gate * HH + col;
            const int kk = ks * 32 + (ll >> 4) * 8 + jj * 2;
            const float v0 = (kk < FF)     ? Wih1[(size_t)row * FF + kk]     : Whh1[(size_t)row * HH + kk - FF];
            const float v1 = (kk + 1 < FF) ? Wih1[(size_t)row * FF + kk + 1] : Whh1[(size_t)row * HH + kk + 1 - FF];
            ((unsigned*)lds)[tile * 256 + w] = pack2h(v0, v1);
        }
    } else {
        for (int u = tid; u < 152 * 256; u += 512) {
            const int tile = u >> 8, w = u & 255;
            const int ll = w >> 2, jj = w & 3;
            const int ks = tile >> 2, gate = tile & 3;
            const int col = c0 + (ll & 15);
            const int kk = ks * 32 + (ll >> 4) * 8 + jj * 2;
            float v0 = 0.f, v1 = 0.f;
            if (col < OO) {
                if (kk < HH) v0 = Wih2[((size_t)gate * OO + col) * HH + kk];
                else if (kk < 1192) v0 = Whh2[((size_t)gate * OO + col) * OO + kk - HH];
                if (kk + 1 < HH) v1 = Wih2[((size_t)gate * OO + col) * HH + kk + 1];
                else if (kk + 1 < 1192) v1 = Whh2[((size_t)gate * OO + col) * OO + kk + 1 - HH];
            }
            ((unsigned*)lds)[tile * 256 + w] = pack2h(v0, v1);
        }
    }
    __syncthreads();

    // ---- bias hoist (epilogue waves) ----
    float bs[2][4][4];
    if (wv < 4) {
        if (isL1) {
            #pragma unroll
            for (int chi = 0; chi < 2; ++chi)
                #pragma unroll
                for (int r = 0; r < 4; ++r) {
                    const int col = c0 + chi * 16 + hi * 4 + r;
                    #pragma unroll
                    for (int g = 0; g < 4; ++g)
                        bs[chi][r][g] = bih1[g * HH + col] + bhh1[g * HH + col];
                }
        } else {
            #pragma unroll
            for (int r = 0; r < 4; ++r) {
                const int col = c0 + hi * 4 + r;
                const bool ok = col < OO;
                #pragma unroll
                for (int g = 0; g < 4; ++g)
                    bs[0][r][g] = ok ? (bih2[g * OO + col] + bhh2[g * OO + col]) : 0.f;
            }
        }
    }

    const int gh = wv >> 2;                 // L1: gate-pair; L2: K-half
    float cr[8] = {0.f,0.f,0.f,0.f,0.f,0.f,0.f,0.f};
    f32x4 (*part1)[4][64] = (f32x4(*)[4][64])(lds + 136 * 1024);
    f32x4* part2 = (f32x4*)(lds + 152 * 1024);

    for (int s = 0; s <= TT; ++s) {
        const int A = s & 1, Bx = A ^ 1;
        const bool active = isL1 ? (s < TT) : (s >= 1);
        f32x4 acc0 = {0,0,0,0}, acc1 = {0,0,0,0}, acc2 = {0,0,0,0}, acc3 = {0,0,0,0};

        if (active) {
            if (isL1) {
                {   // k-step 0: x from data (fp32 -> fp16 B fragment)
                    const float* xp = data + (size_t)b * (TT * FF) + (size_t)s * FF + hi * 8;
                    const float4 xa = *(const float4*)xp;
                    const float4 xb = *(const float4*)(xp + 4);
                    half8 bxf;
                    bxf[0] = (_Float16)xa.x; bxf[1] = (_Float16)xa.y;
                    bxf[2] = (_Float16)xa.z; bxf[3] = (_Float16)xa.w;
                    bxf[4] = (_Float16)xb.x; bxf[5] = (_Float16)xb.y;
                    bxf[6] = (_Float16)xb.z; bxf[7] = (_Float16)xb.w;
                    const char* at = lds + (size_t)(gh * 4) * 1024 + (size_t)l * 16;
                    MFMA4(bxf, at);
                }
                const char* h1p = wsb + H1S_OFF + (size_t)A * H1SLAB + (size_t)l * 16;
                #pragma unroll 4
                for (int ks = 1; ks <= 16; ++ks) {
                    const half8 bf = ld_act(h1p + (size_t)(((ks - 1) * 4 + bfrag)) * 1024);
                    const char* at = lds + (size_t)(ks * 8 + gh * 4) * 1024 + (size_t)l * 16;
                    MFMA4(bf, at);
                }
            } else {
                if (gh == 0) {
                    const char* c1p = wsb + C1S_OFF + (size_t)A * C1SLAB + (size_t)l * 16;
                    #pragma unroll 4
                    for (int ks = 0; ks < 16; ++ks) {
                        const half8 bf = ld_act(c1p + (size_t)(ks * 4 + bfrag) * 1024);
                        const char* at = lds + (size_t)ks * 4096 + (size_t)l * 16;
                        MFMA4(bf, at);
                    }
                    const char* h2p = wsb + H2S_OFF + (size_t)Bx * H2SLAB + (size_t)l * 16;
                    #pragma unroll
                    for (int ks = 16; ks < 19; ++ks) {
                        const half8 bf = ld_act(h2p + (size_t)((ks - 16) * 4 + bfrag) * 1024);
                        const char* at = lds + (size_t)ks * 4096 + (size_t)l * 16;
                        MFMA4(bf, at);
                    }
                } else {
                    const char* h2p = wsb + H2S_OFF + (size_t)Bx * H2SLAB + (size_t)l * 16;
                    #pragma unroll 4
                    for (int ks = 19; ks < 38; ++ks) {
                        const half8 bf = ld_act(h2p + (size_t)((ks - 16) * 4 + bfrag) * 1024);
                        const char* at = lds + (size_t)ks * 4096 + (size_t)l * 16;
                        MFMA4(bf, at);
                    }
                }
            }
        }

        if (isL1) {
            if (active) {
                if (wv >= 4) {
                    part1[wv - 4][0][l] = acc0; part1[wv - 4][1][l] = acc1;
                    part1[wv - 4][2][l] = acc2; part1[wv - 4][3][l] = acc3;
                }
                __syncthreads();
                if (wv < 4) {
                    #pragma unroll
                    for (int chi = 0; chi < 2; ++chi) {
                        const f32x4 o0 = (chi == 0) ? acc0 : acc1;   // gate i
                        const f32x4 o1 = (chi == 0) ? acc2 : acc3;   // gate f
                        const f32x4 p0 = part1[wv][chi][l];          // gate g
                        const f32x4 p1 = part1[wv][2 + chi][l];      // gate o
                        float cn[4], hn[4];
                        #pragma unroll
                        for (int r = 0; r < 4; ++r) {
                            const float ig = sigf(o0[r] + bs[chi][r][0]);
                            const float fg = sigf(o1[r] + bs[chi][r][1]);
                            const float gg = tanhf(p0[r] + bs[chi][r][2]);
                            const float og = sigf(p1[r] + bs[chi][r][3]);
                            const float c = fg * cr[chi * 4 + r] + ig * gg;
                            cr[chi * 4 + r] = c;
                            cn[r] = c; hn[r] = og * tanhf(c);
                        }
                        const int cc = c0 + chi * 16 + hi * 4;
                        const size_t aoff = (size_t)(((cc >> 5) * 4 + wv)) * 1024
                                          + (size_t)((((cc >> 3) & 3) * 16 + lo)) * 16
                                          + (size_t)((hi & 1) * 8);
                        astore8(wsb + H1S_OFF + (size_t)Bx * H1SLAB + aoff, pack4h(hn[0], hn[1], hn[2], hn[3]));
                        astore8(wsb + C1S_OFF + (size_t)Bx * C1SLAB + aoff, pack4h(cn[0], cn[1], cn[2], cn[3]));
                    }
                }
            }
        } else {
            if (active) {
                f32x4 pr0 = {0,0,0,0}, pr1 = {0,0,0,0}, pr2 = {0,0,0,0}, pr3 = {0,0,0,0};
                if (wv >= 4) part2[(wv - 4) * 64 + l] = acc0;
                __syncthreads();
                if (wv < 4) pr0 = part2[wv * 64 + l];
                __syncthreads();
                if (wv >= 4) part2[(wv - 4) * 64 + l] = acc1;
                __syncthreads();
                if (wv < 4) pr1 = part2[wv * 64 + l];
                __syncthreads();
                if (wv >= 4) part2[(wv - 4) * 64 + l] = acc2;
                __syncthreads();
                if (wv < 4) pr2 = part2[wv * 64 + l];
                __syncthreads();
                if (wv >= 4) part2[(wv - 4) * 64 + l] = acc3;
                __syncthreads();
                if (wv < 4) pr3 = part2[wv * 64 + l];
                if (wv < 4) {
                    const int u = s - 1;
                    float cn[4], hn[4];
                    #pragma unroll
                    for (int r = 0; r < 4; ++r) {
                        const float ig = sigf(acc0[r] + pr0[r] + bs[0][r][0]);
                        const float fg = sigf(acc1[r] + pr1[r] + bs[0][r][1]);
                        const float gg = tanhf(acc2[r] + pr2[r] + bs[0][r][2]);
                        const float og = sigf(acc3[r] + pr3[r] + bs[0][r][3]);
                        const float c = fg * cr[r] + ig * gg;
                        cr[r] = c;
                        cn[r] = c; hn[r] = og * tanhf(c);
                    }
                    const int cc = c0 + hi * 4;
                    if (cc < OO) {
                        const f32x4 q = {cn[0], cn[1], cn[2], cn[3]};
                        __builtin_nontemporal_store(q, (f32x4*)(out + (size_t)b * (TT * OO) + (size_t)u * OO + cc));
                        const size_t aoff = (size_t)(((cc >> 5) * 4 + wv)) * 1024
                                          + (size_t)((((cc >> 3) & 3) * 16 + lo)) * 16
                                          + (size_t)((hi & 1) * 8);
                        astore8(wsb + H2S_OFF + (size_t)A * H2SLAB + aoff, pack4h(hn[0], hn[1], hn[2], hn[3]));
                    }
                }
            }
        }
        gridbar(bar, blk, (unsigned)(s + 1));
    }
}

extern "C" void kernel_launch(void* const* d_in, const int* in_sizes, int n_in,
                              void* d_out, int out_size, void* d_ws, size_t ws_size,
                              hipStream_t stream)
{
    const float* data = (const float*)d_in[0];
    const float* Wih1 = (const float*)d_in[1];
    const float* Whh1 = (const float*)d_in[2];
    const float* bih1 = (const float*)d_in[3];
    const float* bhh1 = (const float*)d_in[4];
    const float* Wih2 = (const float*)d_in[5];
    const float* Whh2 = (const float*)d_in[6];
    const float* bih2 = (const float*)d_in[7];
    const float* bhh2 = (const float*)d_in[8];
    float* out = (float*)d_out;
    char* wsb  = (char*)d_ws;

    // allow >64KB dynamic LDS (idempotent; not a stream op, capture-safe)
    hipFuncSetAttribute((const void*)rnn_mfma, hipFuncAttributeMaxDynamicSharedMemorySize, (int)LDS_BYTES);
    // zero act slabs + barrier words (graph-capture-legal, replay-safe)
    hipMemsetAsync(wsb, 0, MEMSET_BYTES, stream);
    rnn_mfma<<<NBLK, 512, LDS_BYTES, stream>>>(data,
                                               Wih1, Whh1, bih1, bhh1,
                                               Wih2, Whh2, bih2, bhh2,
                                               wsb, out);
}